// Round 4
// baseline (481.975 us; speedup 1.0000x reference)
//
#include <hip/hip_runtime.h>
#include <cstdint>

// Problem constants (fixed shapes)
#define E_DIM   576
#define HEADS   18
#define NPTS    12
#define DDEPTH  5
#define HDIM    32
#define BSZ     2
#define GH      64
#define GW      80
#define NQ      (GH*GW)       // 5120
#define NTOK    (NQ*DDEPTH)   // 25600
#define MIXW    864           // 648 offsets + 216 attn logits

typedef __attribute__((ext_vector_type(8))) short short8;
typedef __attribute__((ext_vector_type(4))) float f32x4;

__device__ __forceinline__ float b2f_lo(uint32_t u) {
    union { uint32_t u; float f; } v; v.u = u << 16; return v.f;
}
__device__ __forceinline__ float b2f_hi(uint32_t u) {
    union { uint32_t u; float f; } v; v.u = u & 0xffff0000u; return v.f;
}
__device__ __forceinline__ ushort f2b(float f) {
    union { float f; uint32_t u; } v; v.f = f;
    return (ushort)((v.u + 0x7fffu + ((v.u >> 16) & 1u)) >> 16);
}

// ---------------------------------------------------------------------------
// casts
__global__ void cast_kernel(const float* __restrict__ in, ushort* __restrict__ out, int n4) {
    int i = blockIdx.x * blockDim.x + threadIdx.x;
    if (i >= n4) return;
    const float4 v = reinterpret_cast<const float4*>(in)[i];
    ushort4 o; o.x = f2b(v.x); o.y = f2b(v.y); o.z = f2b(v.z); o.w = f2b(v.w);
    reinterpret_cast<ushort4*>(out)[i] = o;
}

__global__ void cast_add_kernel(const float* __restrict__ a, const float* __restrict__ b,
                                ushort* __restrict__ out, int n4) {
    int i = blockIdx.x * blockDim.x + threadIdx.x;
    if (i >= n4) return;
    const float4 va = reinterpret_cast<const float4*>(a)[i];
    const float4 vb = reinterpret_cast<const float4*>(b)[i];
    ushort4 o;
    o.x = f2b(va.x + vb.x); o.y = f2b(va.y + vb.y);
    o.z = f2b(va.z + vb.z); o.w = f2b(va.w + vb.w);
    reinterpret_cast<ushort4*>(out)[i] = o;
}

// all weight prep in one launch:
//  [0, 331776)            wt_v[n*576+k]   = W_v[k*576+n]
//  [331776, 663552)       wt_out[n*576+k] = W_out[k*576+n]
//  [663552, 1161216)      wt_mix[n*576+k] = n<648 ? W_off[k*648+n] : W_attn[k*216+n-648]
//  idx < 864 also writes bias_mix
__global__ void prep_weights(const float* __restrict__ W_v, const float* __restrict__ W_out,
                             const float* __restrict__ W_off, const float* __restrict__ W_attn,
                             const float* __restrict__ b_off, const float* __restrict__ b_attn,
                             ushort* __restrict__ wt_v, ushort* __restrict__ wt_out,
                             ushort* __restrict__ wt_mix, float* __restrict__ bias_mix) {
    int idx = blockIdx.x * blockDim.x + threadIdx.x;
    if (idx < 864) bias_mix[idx] = (idx < 648) ? b_off[idx] : b_attn[idx - 648];
    if (idx < 331776) {
        int n = idx / E_DIM, k = idx - n * E_DIM;
        wt_v[idx] = f2b(W_v[(size_t)k * E_DIM + n]);
    } else if (idx < 663552) {
        int j = idx - 331776;
        int n = j / E_DIM, k = j - n * E_DIM;
        wt_out[j] = f2b(W_out[(size_t)k * E_DIM + n]);
    } else if (idx < 1161216) {
        int j = idx - 663552;
        int n = j / E_DIM, k = j - n * E_DIM;
        float v = (n < 648) ? W_off[(size_t)k * 648 + n] : W_attn[(size_t)k * 216 + (n - 648)];
        wt_mix[j] = f2b(v);
    }
}

// ---------------------------------------------------------------------------
// MFMA GEMM: C[M,N] = A[M,K] @ Bt[N,K]^T + bias[N]
// Tile 128x96, BK=32, 256 threads = 4 waves.
#define TM 128
#define TN 96
#define BK 32

__device__ __forceinline__ void async_cp16(const ushort* gsrc, ushort* ldst) {
    __builtin_amdgcn_global_load_lds(
        (const __attribute__((address_space(1))) void*)gsrc,
        (__attribute__((address_space(3))) void*)ldst, 16, 0, 0);
}

template <typename OutT>
__global__ void gemm_mfma(const ushort* __restrict__ A, const ushort* __restrict__ Bt,
                          const float* __restrict__ bias, OutT* __restrict__ C,
                          int M, int N, int K, int ldc) {
    __shared__ __align__(16) ushort Asb[TM * BK];   // [m][k]
    __shared__ __align__(16) ushort Bsb[TN * BK];   // [n][k]
    const int tid  = threadIdx.x;
    const int wave = tid >> 6;
    const int lane = tid & 63;
    const int m16  = lane & 15;
    const int quad = lane >> 4;
    const int row0 = blockIdx.x * TM;
    const int n0   = blockIdx.y * TN;

    const f32x4 zero = {0.f, 0.f, 0.f, 0.f};
    f32x4 acc[2][6];
    #pragma unroll
    for (int rt = 0; rt < 2; ++rt)
        #pragma unroll
        for (int ct = 0; ct < 6; ++ct) acc[rt][ct] = zero;

    const int srow = lane >> 2;          // 0..15
    const int scol = (lane & 3) * 8;     // 0,8,16,24

    for (int k0 = 0; k0 < K; k0 += BK) {
        #pragma unroll
        for (int c = 0; c < 2; ++c) {
            const int ch = wave + c * 4;
            async_cp16(A + (size_t)(row0 + ch * 16 + srow) * K + k0 + scol,
                       Asb + ch * 512 + lane * 8);
        }
        {
            const int ch = wave;
            if (ch < 6)
                async_cp16(Bt + (size_t)(n0 + ch * 16 + srow) * K + k0 + scol,
                           Bsb + ch * 512 + lane * 8);
            const int ch2 = wave + 4;
            if (ch2 < 6)
                async_cp16(Bt + (size_t)(n0 + ch2 * 16 + srow) * K + k0 + scol,
                           Bsb + ch2 * 512 + lane * 8);
        }
        __syncthreads();

        short8 afrag[2], bfrag[6];
        #pragma unroll
        for (int rt = 0; rt < 2; ++rt)
            afrag[rt] = *reinterpret_cast<const short8*>(
                Asb + (wave * 32 + rt * 16 + m16) * BK + quad * 8);
        #pragma unroll
        for (int ct = 0; ct < 6; ++ct)
            bfrag[ct] = *reinterpret_cast<const short8*>(
                Bsb + (ct * 16 + m16) * BK + quad * 8);

        #pragma unroll
        for (int rt = 0; rt < 2; ++rt)
            #pragma unroll
            for (int ct = 0; ct < 6; ++ct)
                acc[rt][ct] = __builtin_amdgcn_mfma_f32_16x16x32_bf16(
                    afrag[rt], bfrag[ct], acc[rt][ct], 0, 0, 0);

        __syncthreads();
    }

    #pragma unroll
    for (int ct = 0; ct < 6; ++ct) {
        const int col = n0 + ct * 16 + m16;
        const float bcol = bias[col];
        #pragma unroll
        for (int rt = 0; rt < 2; ++rt) {
            #pragma unroll
            for (int r = 0; r < 4; ++r) {
                const int row = row0 + wave * 32 + rt * 16 + quad * 4 + r;
                const float val = acc[rt][ct][r] + bcol;
                if constexpr (__is_same(OutT, float)) {
                    C[(size_t)row * ldc + col] = val;
                } else {
                    C[(size_t)row * ldc + col] = f2b(val);
                }
            }
        }
    }
}

// ---------------------------------------------------------------------------
// Deformable 3D trilinear attention, two-phase.
// 16 lanes per (b,q,head) group, 16 groups per 256-block.
// Phase 1: lanes 0..11 each handle one point: softmax (shuffle-reduced),
//          corner weights, compacted (weight, dword-offset) list in LDS.
// Phase 2: all 16 lanes stream the list; lane = channel pair (dword).
__global__ void deform_kernel(const ushort* __restrict__ vbuf,
                              const float* __restrict__ mix,
                              ushort* __restrict__ aout) {
    __shared__ uint2 corners[16][96];
    __shared__ int   cnt[16];

    const int gl   = threadIdx.x >> 4;   // group in block
    const int l    = threadIdx.x & 15;
    const int g    = blockIdx.x * 16 + gl;
    const int head = g % HEADS;
    const int bq   = g / HEADS;
    const int q    = bq % NQ;
    const int b    = bq / NQ;
    const int qx   = q % GW;
    const int qy   = q / GW;

    if (l == 0) cnt[gl] = 0;
    __syncthreads();

    const float* mrow = mix + (size_t)bq * MIXW;

    // --- phase 1: softmax + corner emission (lanes 0..11 active) ---
    float lg = (l < NPTS) ? mrow[648 + head * NPTS + l] : -1e30f;
    float mx = lg;
    #pragma unroll
    for (int mk = 1; mk < 16; mk <<= 1) mx = fmaxf(mx, __shfl_xor(mx, mk));
    float e = (l < NPTS) ? __expf(lg - mx) : 0.f;
    float s = e;
    #pragma unroll
    for (int mk = 1; mk < 16; mk <<= 1) s += __shfl_xor(s, mk);

    if (l < NPTS) {
        const float ap = e / s;
        const int ob = (head * NPTS + l) * 3;
        const float ox = mrow[ob + 0];
        const float oy = mrow[ob + 1];
        const float oz = mrow[ob + 2];
        const float x = (float)qx + ox;          // = loc_x*W - 0.5
        const float y = (float)qy + oy;
        const float z = oz * (5.0f / 3.0f) - 0.5f;
        const float x0f = floorf(x), y0f = floorf(y), z0f = floorf(z);
        const int x0 = (int)x0f, y0 = (int)y0f, z0 = (int)z0f;
        const float fx = x - x0f, fy = y - y0f, fz = z - z0f;

        uint2 loc[8];
        int nv = 0;
        #pragma unroll
        for (int dz = 0; dz < 2; ++dz) {
            const int zi = z0 + dz;
            if (zi < 0 || zi >= DDEPTH) continue;
            const float wz = dz ? fz : 1.f - fz;
            #pragma unroll
            for (int dy = 0; dy < 2; ++dy) {
                const int yi = y0 + dy;
                if (yi < 0 || yi >= GH) continue;
                const float wy = dy ? fy : 1.f - fy;
                #pragma unroll
                for (int dx = 0; dx < 2; ++dx) {
                    const int xi = x0 + dx;
                    if (xi < 0 || xi >= GW) continue;
                    const float wgt = ap * wz * wy * (dx ? fx : 1.f - fx);
                    const uint32_t tok = (uint32_t)((zi * GH + yi) * GW + xi);
                    loc[nv].x = __float_as_uint(wgt);
                    loc[nv].y = tok * (E_DIM / 2);   // dword offset within batch
                    ++nv;
                }
            }
        }
        if (nv > 0) {
            const int base = atomicAdd(&cnt[gl], nv);
            for (int i = 0; i < nv; ++i) corners[gl][base + i] = loc[i];
        }
    }
    __syncthreads();

    // --- phase 2: gather + accumulate (all 16 lanes; lane = channel pair) ---
    const int ncnt = cnt[gl];
    const uint32_t* vb = reinterpret_cast<const uint32_t*>(vbuf)
                         + (size_t)b * NTOK * (E_DIM / 2) + head * (HDIM / 2) + l;
    float o0 = 0.f, o1 = 0.f;
    for (int i = 0; i < ncnt; ++i) {
        const uint2 c = corners[gl][i];
        const float w = __uint_as_float(c.x);
        const uint32_t pair = vb[c.y];
        o0 += w * b2f_lo(pair);
        o1 += w * b2f_hi(pair);
    }
    const uint32_t packed = (uint32_t)f2b(o0) | ((uint32_t)f2b(o1) << 16);
    reinterpret_cast<uint32_t*>(aout + (size_t)bq * E_DIM + head * HDIM)[l] = packed;
}

// ---------------------------------------------------------------------------
extern "C" void kernel_launch(void* const* d_in, const int* in_sizes, int n_in,
                              void* d_out, int out_size, void* d_ws, size_t ws_size,
                              hipStream_t stream) {
    const float* query     = (const float*)d_in[0];
    const float* value     = (const float*)d_in[1];
    const float* query_pos = (const float*)d_in[2];
    const float* W_off     = (const float*)d_in[3];
    const float* b_off     = (const float*)d_in[4];
    const float* W_attn    = (const float*)d_in[5];
    const float* b_attn    = (const float*)d_in[6];
    const float* W_v       = (const float*)d_in[7];
    const float* b_v       = (const float*)d_in[8];
    const float* W_out     = (const float*)d_in[9];
    const float* b_out     = (const float*)d_in[10];
    float* out = (float*)d_out;

    char* ws = (char*)d_ws;
    ushort* vbuf     = (ushort*)(ws);                  // 58,982,400
    ushort* val_bf16 = (ushort*)(ws + 58982400);       // 58,982,400
    ushort* aout     = val_bf16;                       // alias (dead after value GEMM)
    ushort* q_bf16   = (ushort*)(ws + 117964800);      // 11,796,480
    float*  mixb     = (float*) (ws + 129761280);      // 35,389,440
    ushort* wt_v     = (ushort*)(ws + 165150720);      // 663,552
    ushort* wt_out   = (ushort*)(ws + 165814272);      // 663,552
    ushort* wt_mix   = (ushort*)(ws + 166477824);      // 995,328
    float*  bias_mix = (float*) (ws + 167473152);      // 3,456

    cast_kernel<<<(51200 * 576 / 4 + 255) / 256, 256, 0, stream>>>(value, val_bf16, 51200 * 576 / 4);
    cast_add_kernel<<<(10240 * 576 / 4 + 255) / 256, 256, 0, stream>>>(query, query_pos, q_bf16, 10240 * 576 / 4);
    prep_weights<<<(1161216 + 255) / 256, 256, 0, stream>>>(
        W_v, W_out, W_off, W_attn, b_off, b_attn, wt_v, wt_out, wt_mix, bias_mix);

    // mix = q @ [W_off|W_attn] + bias : (10240 x 864), fp32 out
    gemm_mfma<float><<<dim3(10240 / TM, MIXW / TN), 256, 0, stream>>>(
        q_bf16, wt_mix, bias_mix, mixb, BSZ * NQ, MIXW, E_DIM, MIXW);

    // v = value @ W_v + b_v : (51200 x 576), bf16 out
    gemm_mfma<ushort><<<dim3(51200 / TM, E_DIM / TN), 256, 0, stream>>>(
        val_bf16, wt_v, b_v, vbuf, BSZ * NTOK, E_DIM, E_DIM, E_DIM);

    // deformable gather + softmax-weighted sum -> aout (bf16)
    deform_kernel<<<BSZ * NQ * HEADS / 16, 256, 0, stream>>>(vbuf, mixb, aout);

    // out = aout @ W_out + b_out : (10240 x 576), fp32 to d_out
    gemm_mfma<float><<<dim3(10240 / TM, E_DIM / TN), 256, 0, stream>>>(
        aout, wt_out, b_out, out, BSZ * NQ, E_DIM, E_DIM, E_DIM);
}

// Round 5
// 395.469 us; speedup vs baseline: 1.2187x; 1.2187x over previous
//
#include <hip/hip_runtime.h>
#include <cstdint>

// Problem constants (fixed shapes)
#define E_DIM   576
#define HEADS   18
#define NPTS    12
#define DDEPTH  5
#define HDIM    32
#define BSZ     2
#define GH      64
#define GW      80
#define NQ      (GH*GW)       // 5120
#define NTOK    (NQ*DDEPTH)   // 25600
#define MIXW    864           // 648 offsets + 216 attn logits
#define BQ_TOT  (BSZ*NQ)      // 10240

typedef __attribute__((ext_vector_type(8))) short short8;
typedef __attribute__((ext_vector_type(4))) float f32x4;

__device__ __forceinline__ float b2f_lo(uint32_t u) {
    union { uint32_t u; float f; } v; v.u = u << 16; return v.f;
}
__device__ __forceinline__ float b2f_hi(uint32_t u) {
    union { uint32_t u; float f; } v; v.u = u & 0xffff0000u; return v.f;
}
__device__ __forceinline__ ushort f2b(float f) {
    union { float f; uint32_t u; } v; v.f = f;
    return (ushort)((v.u + 0x7fffu + ((v.u >> 16) & 1u)) >> 16);
}

// ---------------------------------------------------------------------------
// casts
__global__ void cast_kernel(const float* __restrict__ in, ushort* __restrict__ out, int n4) {
    int i = blockIdx.x * blockDim.x + threadIdx.x;
    if (i >= n4) return;
    const float4 v = reinterpret_cast<const float4*>(in)[i];
    ushort4 o; o.x = f2b(v.x); o.y = f2b(v.y); o.z = f2b(v.z); o.w = f2b(v.w);
    reinterpret_cast<ushort4*>(out)[i] = o;
}

__global__ void cast_add_kernel(const float* __restrict__ a, const float* __restrict__ b,
                                ushort* __restrict__ out, int n4) {
    int i = blockIdx.x * blockDim.x + threadIdx.x;
    if (i >= n4) return;
    const float4 va = reinterpret_cast<const float4*>(a)[i];
    const float4 vb = reinterpret_cast<const float4*>(b)[i];
    ushort4 o;
    o.x = f2b(va.x + vb.x); o.y = f2b(va.y + vb.y);
    o.z = f2b(va.z + vb.z); o.w = f2b(va.w + vb.w);
    reinterpret_cast<ushort4*>(out)[i] = o;
}

// all weight prep in one launch
__global__ void prep_weights(const float* __restrict__ W_v, const float* __restrict__ W_out,
                             const float* __restrict__ W_off, const float* __restrict__ W_attn,
                             const float* __restrict__ b_off, const float* __restrict__ b_attn,
                             ushort* __restrict__ wt_v, ushort* __restrict__ wt_out,
                             ushort* __restrict__ wt_mix, float* __restrict__ bias_mix) {
    int idx = blockIdx.x * blockDim.x + threadIdx.x;
    if (idx < 864) bias_mix[idx] = (idx < 648) ? b_off[idx] : b_attn[idx - 648];
    if (idx < 331776) {
        int n = idx / E_DIM, k = idx - n * E_DIM;
        wt_v[idx] = f2b(W_v[(size_t)k * E_DIM + n]);
    } else if (idx < 663552) {
        int j = idx - 331776;
        int n = j / E_DIM, k = j - n * E_DIM;
        wt_out[j] = f2b(W_out[(size_t)k * E_DIM + n]);
    } else if (idx < 1161216) {
        int j = idx - 663552;
        int n = j / E_DIM, k = j - n * E_DIM;
        float v = (n < 648) ? W_off[(size_t)k * 648 + n] : W_attn[(size_t)k * 216 + (n - 648)];
        wt_mix[j] = f2b(v);
    }
}

// ---------------------------------------------------------------------------
// MFMA GEMM: C[M,N] = A[M,K] @ Bt[N,K]^T + bias[N]
// Tile 128x96, BK=32, 256 threads = 4 waves.
#define TM 128
#define TN 96
#define BK 32

__device__ __forceinline__ void async_cp16(const ushort* gsrc, ushort* ldst) {
    __builtin_amdgcn_global_load_lds(
        (const __attribute__((address_space(1))) void*)gsrc,
        (__attribute__((address_space(3))) void*)ldst, 16, 0, 0);
}

template <typename OutT>
__global__ void gemm_mfma(const ushort* __restrict__ A, const ushort* __restrict__ Bt,
                          const float* __restrict__ bias, OutT* __restrict__ C,
                          int M, int N, int K, int ldc) {
    __shared__ __align__(16) ushort Asb[TM * BK];   // [m][k]
    __shared__ __align__(16) ushort Bsb[TN * BK];   // [n][k]
    const int tid  = threadIdx.x;
    const int wave = tid >> 6;
    const int lane = tid & 63;
    const int m16  = lane & 15;
    const int quad = lane >> 4;
    const int row0 = blockIdx.x * TM;
    const int n0   = blockIdx.y * TN;

    const f32x4 zero = {0.f, 0.f, 0.f, 0.f};
    f32x4 acc[2][6];
    #pragma unroll
    for (int rt = 0; rt < 2; ++rt)
        #pragma unroll
        for (int ct = 0; ct < 6; ++ct) acc[rt][ct] = zero;

    const int srow = lane >> 2;          // 0..15
    const int scol = (lane & 3) * 8;     // 0,8,16,24

    for (int k0 = 0; k0 < K; k0 += BK) {
        #pragma unroll
        for (int c = 0; c < 2; ++c) {
            const int ch = wave + c * 4;
            async_cp16(A + (size_t)(row0 + ch * 16 + srow) * K + k0 + scol,
                       Asb + ch * 512 + lane * 8);
        }
        {
            const int ch = wave;
            if (ch < 6)
                async_cp16(Bt + (size_t)(n0 + ch * 16 + srow) * K + k0 + scol,
                           Bsb + ch * 512 + lane * 8);
            const int ch2 = wave + 4;
            if (ch2 < 6)
                async_cp16(Bt + (size_t)(n0 + ch2 * 16 + srow) * K + k0 + scol,
                           Bsb + ch2 * 512 + lane * 8);
        }
        __syncthreads();

        short8 afrag[2], bfrag[6];
        #pragma unroll
        for (int rt = 0; rt < 2; ++rt)
            afrag[rt] = *reinterpret_cast<const short8*>(
                Asb + (wave * 32 + rt * 16 + m16) * BK + quad * 8);
        #pragma unroll
        for (int ct = 0; ct < 6; ++ct)
            bfrag[ct] = *reinterpret_cast<const short8*>(
                Bsb + (ct * 16 + m16) * BK + quad * 8);

        #pragma unroll
        for (int rt = 0; rt < 2; ++rt)
            #pragma unroll
            for (int ct = 0; ct < 6; ++ct)
                acc[rt][ct] = __builtin_amdgcn_mfma_f32_16x16x32_bf16(
                    afrag[rt], bfrag[ct], acc[rt][ct], 0, 0, 0);

        __syncthreads();
    }

    #pragma unroll
    for (int ct = 0; ct < 6; ++ct) {
        const int col = n0 + ct * 16 + m16;
        const float bcol = bias[col];
        #pragma unroll
        for (int rt = 0; rt < 2; ++rt) {
            #pragma unroll
            for (int r = 0; r < 4; ++r) {
                const int row = row0 + wave * 32 + rt * 16 + quad * 4 + r;
                const float val = acc[rt][ct][r] + bcol;
                if constexpr (__is_same(OutT, float)) {
                    C[(size_t)row * ldc + col] = val;
                } else {
                    C[(size_t)row * ldc + col] = f2b(val);
                }
            }
        }
    }
}

// ---------------------------------------------------------------------------
// Deformable 3D trilinear attention — register/shuffle version, head-major.
// 16 lanes per (b,q) x head group; head = blockIdx.x / 640 (uniform per block),
// 4 subgroups per wave share the head and have consecutive q -> near-uniform
// branches and high L1 overlap.
// Phase 1: lane l<12 computes point l: softmax prob (shfl-reduced), 8 corner
//          (weight, dword-offset) pairs + 8-bit validity mask, all in regs.
// Phase 2: all 16 lanes loop points, broadcast via __shfl(width 16), gather.
__global__ void __launch_bounds__(256, 8)
deform_kernel(const ushort* __restrict__ vbuf,
              const float* __restrict__ mix,
              ushort* __restrict__ aout) {
    const int gl   = threadIdx.x >> 4;   // subgroup in block
    const int l    = threadIdx.x & 15;
    const int head = blockIdx.x / 640;                   // block-uniform
    const int bq   = (blockIdx.x % 640) * 16 + gl;       // b*NQ + q
    const int q    = bq % NQ;
    const int b    = bq / NQ;
    const int qx   = q % GW;
    const int qy   = q / GW;

    const float* mrow = mix + (size_t)bq * MIXW;

    // --- phase 1: softmax (lanes 0..11 hold one logit each) ---
    float lg = (l < NPTS) ? mrow[648 + head * NPTS + l] : -1e30f;
    float mx = lg;
    #pragma unroll
    for (int mk = 1; mk < 16; mk <<= 1) mx = fmaxf(mx, __shfl_xor(mx, mk, 16));
    float e = (l < NPTS) ? __expf(lg - mx) : 0.f;
    float s = e;
    #pragma unroll
    for (int mk = 1; mk < 16; mk <<= 1) s += __shfl_xor(s, mk, 16);

    // --- phase 1b: corner geometry for point l (lanes 0..11) ---
    float    cw[8];
    uint32_t coff[8];
    uint32_t mask = 0;
    {
        const float ap = e / s;
        const int pl = (l < NPTS) ? l : 0;
        const int ob = (head * NPTS + pl) * 3;
        const float ox = mrow[ob + 0];
        const float oy = mrow[ob + 1];
        const float oz = mrow[ob + 2];
        const float x = (float)qx + ox;          // = loc_x*W - 0.5
        const float y = (float)qy + oy;
        const float z = oz * (5.0f / 3.0f) - 0.5f;
        const float x0f = floorf(x), y0f = floorf(y), z0f = floorf(z);
        const int x0 = (int)x0f, y0 = (int)y0f, z0 = (int)z0f;
        const float fx = x - x0f, fy = y - y0f, fz = z - z0f;

        #pragma unroll
        for (int dz = 0; dz < 2; ++dz) {
            const int zi = z0 + dz;
            const bool zv = (zi >= 0) & (zi < DDEPTH);
            const int zc = min(max(zi, 0), DDEPTH - 1);
            const float wz = dz ? fz : 1.f - fz;
            #pragma unroll
            for (int dy = 0; dy < 2; ++dy) {
                const int yi = y0 + dy;
                const bool yv = (yi >= 0) & (yi < GH);
                const int yc = min(max(yi, 0), GH - 1);
                const float wy = dy ? fy : 1.f - fy;
                #pragma unroll
                for (int dx = 0; dx < 2; ++dx) {
                    const int xi = x0 + dx;
                    const bool xv = (xi >= 0) & (xi < GW);
                    const int xc = min(max(xi, 0), GW - 1);
                    const float wx = dx ? fx : 1.f - fx;
                    const int i = dz * 4 + dy * 2 + dx;
                    const bool valid = zv & yv & xv & (l < NPTS);
                    cw[i]   = ap * wz * wy * wx;
                    coff[i] = (uint32_t)((zc * GH + yc) * GW + xc) * (E_DIM / 2);
                    mask |= (valid ? (1u << i) : 0u);
                }
            }
        }
    }

    // --- phase 2: gather (all 16 lanes; lane = channel pair) ---
    const uint32_t* vb = reinterpret_cast<const uint32_t*>(vbuf)
                         + (size_t)b * NTOK * (E_DIM / 2) + head * (HDIM / 2) + l;
    float o0 = 0.f, o1 = 0.f;
    #pragma unroll
    for (int p = 0; p < NPTS; ++p) {
        const uint32_t msk = (uint32_t)__shfl((int)mask, p, 16);
        if (msk == 0) continue;   // near wave-uniform skip
        #pragma unroll
        for (int i = 0; i < 8; ++i) {
            if (msk & (1u << i)) {
                const float    w   = __shfl(cw[i], p, 16);
                const uint32_t off = (uint32_t)__shfl((int)coff[i], p, 16);
                const uint32_t pair = vb[off];
                o0 += w * b2f_lo(pair);
                o1 += w * b2f_hi(pair);
            }
        }
    }
    const uint32_t packed = (uint32_t)f2b(o0) | ((uint32_t)f2b(o1) << 16);
    reinterpret_cast<uint32_t*>(aout)[(size_t)bq * (E_DIM / 2) + head * (HDIM / 2) + l] = packed;
}

// ---------------------------------------------------------------------------
extern "C" void kernel_launch(void* const* d_in, const int* in_sizes, int n_in,
                              void* d_out, int out_size, void* d_ws, size_t ws_size,
                              hipStream_t stream) {
    const float* query     = (const float*)d_in[0];
    const float* value     = (const float*)d_in[1];
    const float* query_pos = (const float*)d_in[2];
    const float* W_off     = (const float*)d_in[3];
    const float* b_off     = (const float*)d_in[4];
    const float* W_attn    = (const float*)d_in[5];
    const float* b_attn    = (const float*)d_in[6];
    const float* W_v       = (const float*)d_in[7];
    const float* b_v       = (const float*)d_in[8];
    const float* W_out     = (const float*)d_in[9];
    const float* b_out     = (const float*)d_in[10];
    float* out = (float*)d_out;

    char* ws = (char*)d_ws;
    ushort* vbuf     = (ushort*)(ws);                  // 58,982,400
    ushort* val_bf16 = (ushort*)(ws + 58982400);       // 58,982,400
    ushort* aout     = val_bf16;                       // alias (dead after value GEMM)
    ushort* q_bf16   = (ushort*)(ws + 117964800);      // 11,796,480
    float*  mixb     = (float*) (ws + 129761280);      // 35,389,440
    ushort* wt_v     = (ushort*)(ws + 165150720);      // 663,552
    ushort* wt_out   = (ushort*)(ws + 165814272);      // 663,552
    ushort* wt_mix   = (ushort*)(ws + 166477824);      // 995,328
    float*  bias_mix = (float*) (ws + 167473152);      // 3,456

    cast_kernel<<<(51200 * 576 / 4 + 255) / 256, 256, 0, stream>>>(value, val_bf16, 51200 * 576 / 4);
    cast_add_kernel<<<(10240 * 576 / 4 + 255) / 256, 256, 0, stream>>>(query, query_pos, q_bf16, 10240 * 576 / 4);
    prep_weights<<<(1161216 + 255) / 256, 256, 0, stream>>>(
        W_v, W_out, W_off, W_attn, b_off, b_attn, wt_v, wt_out, wt_mix, bias_mix);

    // mix = q @ [W_off|W_attn] + bias : (10240 x 864), fp32 out
    gemm_mfma<float><<<dim3(10240 / TM, MIXW / TN), 256, 0, stream>>>(
        q_bf16, wt_mix, bias_mix, mixb, BSZ * NQ, MIXW, E_DIM, MIXW);

    // v = value @ W_v + b_v : (51200 x 576), bf16 out
    gemm_mfma<ushort><<<dim3(51200 / TM, E_DIM / TN), 256, 0, stream>>>(
        val_bf16, wt_v, b_v, vbuf, BSZ * NTOK, E_DIM, E_DIM, E_DIM);

    // deformable gather + softmax-weighted sum -> aout (bf16), head-major grid
    deform_kernel<<<HEADS * 640, 256, 0, stream>>>(vbuf, mixb, aout);

    // out = aout @ W_out + b_out : (10240 x 576), fp32 to d_out
    gemm_mfma<float><<<dim3(10240 / TM, E_DIM / TN), 256, 0, stream>>>(
        aout, wt_out, b_out, out, BSZ * NQ, E_DIM, E_DIM, E_DIM);
}